// Round 1
// 972.103 us; speedup vs baseline: 2.6848x; 2.6848x over previous
//
#include <hip/hip_runtime.h>
#include <hip/hip_bf16.h>
#include <stdint.h>
#include <stddef.h>

using bf16 = __hip_bfloat16;
typedef short s16x8 __attribute__((ext_vector_type(8)));   // 8 bf16 = one MFMA frag (4 VGPRs)
typedef float f32x4 __attribute__((ext_vector_type(4)));

#define MFMA16(a, b, c) __builtin_amdgcn_mfma_f32_16x16x32_bf16((a), (b), (c), 0, 0, 0)

typedef __attribute__((address_space(1))) void gvoid;
typedef __attribute__((address_space(3))) void lvoid;
// global -> LDS direct copy, 16B per lane; LDS dest = wave-uniform base + lane*16
#define GLL16(gp, lp) __builtin_amdgcn_global_load_lds((gvoid*)(void*)(gp), (lvoid*)(lp), 16, 0, 0)

__device__ __forceinline__ short f2bf(float x) {
    bf16 h = __float2bfloat16(x);
    return __builtin_bit_cast(short, h);
}

// f32 -> bf16 elementwise, n % 1024 == 0, grid*block*4 == n
__global__ void cvt_bf16(const float* __restrict__ in, bf16* __restrict__ out, int n) {
    int i = (blockIdx.x * blockDim.x + threadIdx.x) * 4;
    if (i < n) {
        float4 v = *(const float4*)(in + i);
        out[i + 0] = __float2bfloat16(v.x);
        out[i + 1] = __float2bfloat16(v.y);
        out[i + 2] = __float2bfloat16(v.z);
        out[i + 3] = __float2bfloat16(v.w);
    }
}

// zero n bf16 (n % 2048 == 0), grid*block*8 == n
__global__ void zero_bf16(bf16* __restrict__ p, int n) {
    int i = (blockIdx.x * blockDim.x + threadIdx.x) * 8;
    if (i < n) {
        s16x8 z = {0, 0, 0, 0, 0, 0, 0, 0};
        *(s16x8*)(p + i) = z;
    }
}

// 1024x1024 bf16 transpose: out = in^T.  grid (16,16), block 256.
__global__ __launch_bounds__(256) void transpose_bf16(
    const bf16* __restrict__ in, bf16* __restrict__ out)
{
    __shared__ bf16 t[64][72];
    const int bx = blockIdx.x * 64, by = blockIdx.y * 64;
    const int tid = threadIdx.x;
#pragma unroll
    for (int i = 0; i < 2; ++i) {
        const int r = (tid >> 3) + i * 32, c = (tid & 7) * 8;
        *(s16x8*)&t[r][c] = *(const s16x8*)(in + (size_t)(bx + r) * 1024 + by + c);
    }
    __syncthreads();
#pragma unroll
    for (int i = 0; i < 2; ++i) {
        const int r = (tid >> 3) + i * 32, c = (tid & 7) * 8;
        s16x8 v;
#pragma unroll
        for (int k = 0; k < 8; ++k) v[k] = __builtin_bit_cast(short, t[c + k][r]);
        *(s16x8*)(out + (size_t)(by + r) * 1024 + bx + c) = v;
    }
}

// ---------------------------------------------------------------------------
// C[om(m)][n] = bias[n] + sum_k A[m][k] * Bt[n][k]     (K = N = 1024)
// A_F32: A is f32, staged via register convert + ds_write_b128 (XOR-swizzled
//        chunk layout identical to the GLL16 path). Else A is bf16 via GLL16.
// OUT_F32: store f32 (+f32 bias) else bf16.  bias always f32.
// REMAP: 0 none; 1 m=b*512+t -> t*64+b ; 2 m=t*64+b -> b*512+t
// 128x128 tile, BK=64, 4 waves each 64x64 (m97-verified structure).
// ---------------------------------------------------------------------------
template<bool A_F32, bool OUT_F32, int REMAP>
__global__ __launch_bounds__(256) void gemm_bt(
    const void* __restrict__ Ap, const bf16* __restrict__ Bt,
    const float* __restrict__ bias, void* __restrict__ Cp)
{
    __shared__ __align__(16) bf16 lA[128 * 64];
    __shared__ __align__(16) bf16 lB[128 * 64];

    const int tid  = threadIdx.x;
    const int lane = tid & 63, wv = tid >> 6;
    const int wm = wv & 1, wn = wv >> 1;
    const int quad = lane >> 4, l16 = lane & 15;
    const int m0 = blockIdx.x * 128, n0 = blockIdx.y * 128;

    const int sr = lane >> 3;
    const int sc = ((lane & 7) ^ sr) * 8;   // element offset of swizzled 16B chunk

    const int ar = tid >> 1;
    const int ah = tid & 1;

    f32x4 acc[4][4] = {};

    for (int ko = 0; ko < 1024; ko += 64) {
        if constexpr (A_F32) {
            const float* Af = (const float*)Ap;
#pragma unroll
            for (int i = 0; i < 4; ++i) {
                const int c = ah * 4 + i;                    // source chunk 0..7
                const float* src = Af + (size_t)(m0 + ar) * 1024 + ko + c * 8;
                float4 v0 = *(const float4*)(src);
                float4 v1 = *(const float4*)(src + 4);
                s16x8 w;
                w[0] = f2bf(v0.x); w[1] = f2bf(v0.y); w[2] = f2bf(v0.z); w[3] = f2bf(v0.w);
                w[4] = f2bf(v1.x); w[5] = f2bf(v1.y); w[6] = f2bf(v1.z); w[7] = f2bf(v1.w);
                *(s16x8*)((char*)lA + ar * 128 + ((c ^ (ar & 7)) << 4)) = w;
            }
#pragma unroll
            for (int qi = 0; qi < 4; ++qi) {
                const int q = wv * 4 + qi;
                GLL16(Bt + (size_t)(n0 + q * 8 + sr) * 1024 + ko + sc, (char*)lB + q * 1024);
            }
        } else {
            const bf16* Ab = (const bf16*)Ap;
#pragma unroll
            for (int qi = 0; qi < 4; ++qi) {
                const int q = wv * 4 + qi;
                GLL16(Ab + (size_t)(m0 + q * 8 + sr) * 1024 + ko + sc, (char*)lA + q * 1024);
                GLL16(Bt + (size_t)(n0 + q * 8 + sr) * 1024 + ko + sc, (char*)lB + q * 1024);
            }
        }
        __syncthreads();   // drains vmcnt + lgkmcnt before s_barrier
#pragma unroll
        for (int kc = 0; kc < 2; ++kc) {
            s16x8 af[4], bg[4];
#pragma unroll
            for (int mt = 0; mt < 4; ++mt) {
                const int r = 64 * wm + 16 * mt + l16;
                const int c = kc * 4 + quad;
                af[mt] = *(const s16x8*)((const char*)lA + r * 128 + ((c ^ (r & 7)) * 16));
            }
#pragma unroll
            for (int nt = 0; nt < 4; ++nt) {
                const int r = 64 * wn + 16 * nt + l16;
                const int c = kc * 4 + quad;
                bg[nt] = *(const s16x8*)((const char*)lB + r * 128 + ((c ^ (r & 7)) * 16));
            }
#pragma unroll
            for (int mt = 0; mt < 4; ++mt)
#pragma unroll
                for (int nt = 0; nt < 4; ++nt)
                    acc[mt][nt] = MFMA16(af[mt], bg[nt], acc[mt][nt]);
        }
        __syncthreads();
    }

    float bv[4];
#pragma unroll
    for (int nt = 0; nt < 4; ++nt)
        bv[nt] = bias[n0 + 64 * wn + 16 * nt + l16];

    // D layout: row = quad*4 + reg, col = lane&15  (m89/m91-verified)
#pragma unroll
    for (int mt = 0; mt < 4; ++mt) {
#pragma unroll
        for (int r = 0; r < 4; ++r) {
            const int m = m0 + 64 * wm + 16 * mt + 4 * quad + r;
            int om = m;
            if constexpr (REMAP == 1)      om = ((m & 511) << 6) | (m >> 9); // b*512+t -> t*64+b
            else if constexpr (REMAP == 2) om = ((m & 63) << 9) | (m >> 6);  // t*64+b -> b*512+t
#pragma unroll
            for (int nt = 0; nt < 4; ++nt) {
                const int n = n0 + 64 * wn + 16 * nt + l16;
                const float val = acc[mt][nt][r] + bv[nt];
                if constexpr (OUT_F32) ((float*)Cp)[(size_t)om * 1024 + n] = val;
                else ((bf16*)Cp)[(size_t)om * 1024 + n] = __float2bfloat16(val);
            }
        }
    }
}

// ---------------------------------------------------------------------------
// Power chain: D[z] = A[z] @ Bt^T,  A = Abase + z*1M, D = Dbase + z*1M (elems).
// Same 128x128 structure as gemm_bt, no bias, bf16 out.  grid (8, 8, batch).
// ---------------------------------------------------------------------------
__global__ __launch_bounds__(256) void powmul(
    const bf16* __restrict__ Abase, const bf16* __restrict__ Bt,
    bf16* __restrict__ Dbase)
{
    __shared__ __align__(16) bf16 lA[128 * 64];
    __shared__ __align__(16) bf16 lB[128 * 64];
    const int tid  = threadIdx.x;
    const int lane = tid & 63, wv = tid >> 6;
    const int wm = wv & 1, wn = wv >> 1;
    const int quad = lane >> 4, l16 = lane & 15;
    const int m0 = blockIdx.x * 128, n0 = blockIdx.y * 128;
    const bf16* A = Abase + (size_t)blockIdx.z * 1048576;
    bf16* D       = Dbase + (size_t)blockIdx.z * 1048576;
    const int sr = lane >> 3;
    const int sc = ((lane & 7) ^ sr) * 8;

    f32x4 acc[4][4] = {};
    for (int ko = 0; ko < 1024; ko += 64) {
#pragma unroll
        for (int qi = 0; qi < 4; ++qi) {
            const int q = wv * 4 + qi;
            GLL16(A  + (size_t)(m0 + q * 8 + sr) * 1024 + ko + sc, (char*)lA + q * 1024);
            GLL16(Bt + (size_t)(n0 + q * 8 + sr) * 1024 + ko + sc, (char*)lB + q * 1024);
        }
        __syncthreads();
#pragma unroll
        for (int kc = 0; kc < 2; ++kc) {
            s16x8 af[4], bg[4];
#pragma unroll
            for (int mt = 0; mt < 4; ++mt) {
                const int r = 64 * wm + 16 * mt + l16;
                const int c = kc * 4 + quad;
                af[mt] = *(const s16x8*)((const char*)lA + r * 128 + ((c ^ (r & 7)) * 16));
            }
#pragma unroll
            for (int nt = 0; nt < 4; ++nt) {
                const int r = 64 * wn + 16 * nt + l16;
                const int c = kc * 4 + quad;
                bg[nt] = *(const s16x8*)((const char*)lB + r * 128 + ((c ^ (r & 7)) * 16));
            }
#pragma unroll
            for (int mt = 0; mt < 4; ++mt)
#pragma unroll
                for (int nt = 0; nt < 4; ++nt)
                    acc[mt][nt] = MFMA16(af[mt], bg[nt], acc[mt][nt]);
        }
        __syncthreads();
    }
#pragma unroll
    for (int mt = 0; mt < 4; ++mt)
#pragma unroll
        for (int r = 0; r < 4; ++r) {
            const int m = m0 + 64 * wm + 16 * mt + 4 * quad + r;
#pragma unroll
            for (int nt = 0; nt < 4; ++nt) {
                const int n = n0 + 64 * wn + 16 * nt + l16;
                D[(size_t)m * 1024 + n] = __float2bfloat16(acc[mt][nt][r]);
            }
        }
}

// ---------------------------------------------------------------------------
// Local scan step j: for every chunk c (blockIdx.x), rows t = c*16+j:
//   UA[t] += UA[t-1] @ Waa^T     (RMW epilogue; UA layout [t][b=64][1024])
// 64x128 tile, 4 waves each 64 rows x 32 cols.  grid (32, 8).
// ---------------------------------------------------------------------------
__global__ __launch_bounds__(256) void local_step(
    const bf16* __restrict__ Bt, bf16* __restrict__ UA, int j)
{
    __shared__ __align__(16) bf16 lA[64 * 64];
    __shared__ __align__(16) bf16 lB[128 * 64];
    const int tid = threadIdx.x;
    const int lane = tid & 63, wv = tid >> 6;
    const int quad = lane >> 4, l16 = lane & 15;
    const int n0 = blockIdx.y * 128;
    const int t = blockIdx.x * 16 + j;
    const bf16* src = UA + (size_t)(t - 1) * 64 * 1024;
    bf16* dst       = UA + (size_t)t * 64 * 1024;
    const int sr = lane >> 3;
    const int sc = ((lane & 7) ^ sr) * 8;

    f32x4 acc[4][2] = {};
    for (int ko = 0; ko < 1024; ko += 64) {
#pragma unroll
        for (int qi = 0; qi < 2; ++qi) {
            const int q = wv * 2 + qi;
            GLL16(src + (size_t)(q * 8 + sr) * 1024 + ko + sc, (char*)lA + q * 1024);
        }
#pragma unroll
        for (int qi = 0; qi < 4; ++qi) {
            const int q = wv * 4 + qi;
            GLL16(Bt + (size_t)(n0 + q * 8 + sr) * 1024 + ko + sc, (char*)lB + q * 1024);
        }
        __syncthreads();
#pragma unroll
        for (int kc = 0; kc < 2; ++kc) {
            s16x8 af[4], bg[2];
#pragma unroll
            for (int mt = 0; mt < 4; ++mt) {
                const int r = 16 * mt + l16;
                const int c = kc * 4 + quad;
                af[mt] = *(const s16x8*)((const char*)lA + r * 128 + ((c ^ (r & 7)) * 16));
            }
#pragma unroll
            for (int nt = 0; nt < 2; ++nt) {
                const int r = 32 * wv + 16 * nt + l16;
                const int c = kc * 4 + quad;
                bg[nt] = *(const s16x8*)((const char*)lB + r * 128 + ((c ^ (r & 7)) * 16));
            }
#pragma unroll
            for (int mt = 0; mt < 4; ++mt)
#pragma unroll
                for (int nt = 0; nt < 2; ++nt)
                    acc[mt][nt] = MFMA16(af[mt], bg[nt], acc[mt][nt]);
        }
        __syncthreads();
    }
#pragma unroll
    for (int mt = 0; mt < 4; ++mt)
#pragma unroll
        for (int r = 0; r < 4; ++r) {
            const int b = 16 * mt + 4 * quad + r;
#pragma unroll
            for (int nt = 0; nt < 2; ++nt) {
                const int n = n0 + 32 * wv + 16 * nt + l16;
                bf16* p = dst + (size_t)b * 1024 + n;
                *p = __float2bfloat16(acc[mt][nt][r] + __bfloat162float(*p));
            }
        }
}

// ---------------------------------------------------------------------------
// Carry step: dst[b][n] = lend[b][n] + sum_k src[b][k] * P16[n][k]
// (dst = CIN[c], src = CIN[c-1], lend = UA rows of t=(c-1)*16+15)
// Identical structure to the verified scan_step: 256 blocks x 1 wave.
// ---------------------------------------------------------------------------
__global__ __launch_bounds__(64, 1) void carry_step(
    const bf16* __restrict__ P16, const bf16* __restrict__ lend,
    const bf16* __restrict__ src, bf16* __restrict__ dst)
{
    const int lane = threadIdx.x;
    const int quad = lane >> 4, l16 = lane & 15;
    const int bi = blockIdx.x & 3, nj = blockIdx.x >> 2;

    const bf16* arow = src + ((size_t)(16 * bi + l16)) * 1024;
    const bf16* wrow = P16 + ((size_t)(16 * nj + l16)) * 1024;

    const bf16* urow = lend + ((size_t)(16 * bi + 4 * quad)) * 1024 + 16 * nj + l16;
    f32x4 acc;
#pragma unroll
    for (int rr = 0; rr < 4; ++rr)
        acc[rr] = __bfloat162float(urow[(size_t)rr * 1024]);

    s16x8 av[32], wf[32];
#pragma unroll
    for (int kc = 0; kc < 32; ++kc) {
        av[kc] = *(const s16x8*)(arow + kc * 32 + quad * 8);
        wf[kc] = *(const s16x8*)(wrow + kc * 32 + quad * 8);
    }
#pragma unroll
    for (int kc = 0; kc < 32; ++kc)
        acc = MFMA16(av[kc], wf[kc], acc);

    bf16* drow = dst + ((size_t)(16 * bi + 4 * quad)) * 1024 + 16 * nj + l16;
#pragma unroll
    for (int rr = 0; rr < 4; ++rr)
        drow[(size_t)rr * 1024] = __float2bfloat16(acc[rr]);
}

// ---------------------------------------------------------------------------
// Fix-up (one launch, fully parallel):
//   UA[(c*16+j)*64 + b][n] += sum_k CIN[c*64 + b][k] * P_{j+1}[n][k]
// A = CIN (2048 contiguous rows), Bt = PB + j*1M, j = blockIdx.z.
// 128x128 tile gemm_bt structure with RMW row-mapped epilogue. grid (16,8,16).
// ---------------------------------------------------------------------------
__global__ __launch_bounds__(256) void fixup_k(
    const bf16* __restrict__ CIN, const bf16* __restrict__ PBase,
    bf16* __restrict__ UA)
{
    __shared__ __align__(16) bf16 lA[128 * 64];
    __shared__ __align__(16) bf16 lB[128 * 64];
    const int tid  = threadIdx.x;
    const int lane = tid & 63, wv = tid >> 6;
    const int wm = wv & 1, wn = wv >> 1;
    const int quad = lane >> 4, l16 = lane & 15;
    const int m0 = blockIdx.x * 128, n0 = blockIdx.y * 128;
    const int j = blockIdx.z;
    const bf16* Bt = PBase + (size_t)j * 1048576;
    const int sr = lane >> 3;
    const int sc = ((lane & 7) ^ sr) * 8;

    f32x4 acc[4][4] = {};
    for (int ko = 0; ko < 1024; ko += 64) {
#pragma unroll
        for (int qi = 0; qi < 4; ++qi) {
            const int q = wv * 4 + qi;
            GLL16(CIN + (size_t)(m0 + q * 8 + sr) * 1024 + ko + sc, (char*)lA + q * 1024);
            GLL16(Bt  + (size_t)(n0 + q * 8 + sr) * 1024 + ko + sc, (char*)lB + q * 1024);
        }
        __syncthreads();
#pragma unroll
        for (int kc = 0; kc < 2; ++kc) {
            s16x8 af[4], bg[4];
#pragma unroll
            for (int mt = 0; mt < 4; ++mt) {
                const int r = 64 * wm + 16 * mt + l16;
                const int c = kc * 4 + quad;
                af[mt] = *(const s16x8*)((const char*)lA + r * 128 + ((c ^ (r & 7)) * 16));
            }
#pragma unroll
            for (int nt = 0; nt < 4; ++nt) {
                const int r = 64 * wn + 16 * nt + l16;
                const int c = kc * 4 + quad;
                bg[nt] = *(const s16x8*)((const char*)lB + r * 128 + ((c ^ (r & 7)) * 16));
            }
#pragma unroll
            for (int mt = 0; mt < 4; ++mt)
#pragma unroll
                for (int nt = 0; nt < 4; ++nt)
                    acc[mt][nt] = MFMA16(af[mt], bg[nt], acc[mt][nt]);
        }
        __syncthreads();
    }
#pragma unroll
    for (int mt = 0; mt < 4; ++mt)
#pragma unroll
        for (int r = 0; r < 4; ++r) {
            const int vm = m0 + 64 * wm + 16 * mt + 4 * quad + r;   // c*64 + b
            const size_t grow = (size_t)(((vm >> 6) * 16 + j) * 64 + (vm & 63));
#pragma unroll
            for (int nt = 0; nt < 4; ++nt) {
                const int n = n0 + 64 * wn + 16 * nt + l16;
                bf16* p = UA + grow * 1024 + n;
                *p = __float2bfloat16(acc[mt][nt][r] + __bfloat162float(*p));
            }
        }
}

// ---------------------------------------------------------------------------
// Blocked linear scan, S=16 chunk, G=32 chunks:
//   A[t] = U[t] + A[t-1]@W^T  ==  local chunk scans (depth 15, parallel over
//   chunks) + carry scan over chunk ends with W^16 (depth 31, tiny) + one
//   parallel fix-up with powers W^1..W^16.
// Replaces 511 sequential scan_step launches (launch-latency bound) with 61
// total launches.
// ---------------------------------------------------------------------------
extern "C" void kernel_launch(void* const* d_in, const int* in_sizes, int n_in,
                              void* d_out, int out_size, void* d_ws, size_t ws_size,
                              hipStream_t stream) {
    const float* X   = (const float*)d_in[0];   // [64,512,1024] f32
    const float* Wax = (const float*)d_in[1];   // [1024,1024]   f32
    const float* Waa = (const float*)d_in[2];   // [1024,1024]   f32
    const float* ba  = (const float*)d_in[3];   // [1024]        f32
    const float* Wy  = (const float*)d_in[4];   // [1024,1024]   f32
    const float* by  = (const float*)d_in[5];   // [1024]        f32

    char* ws = (char*)d_ws;
    bf16* UA   = (bf16*)ws;                       // 64 MB: [512][64][1024]
    bf16* PB   = (bf16*)(ws + 67108864);          // 32 MB: PB[k] = W^{k+1}, k=0..15
    bf16* Waxb = (bf16*)(ws + 100663296);         // 2 MB
    bf16* Wyb  = (bf16*)(ws + 102760448);         // 2 MB
    bf16* CIN  = (bf16*)(ws + 104857600);         // 4 MB: [32][64][1024] carry-in per chunk
    bf16* Tb   = CIN;                             // 2 MB transpose scratch (dead before carries)
    const size_t MM = 1048576;                    // elems per 1024x1024 matrix

    const int NW = 1024 * 1024;
    cvt_bf16<<<dim3(NW / 1024), dim3(256), 0, stream>>>(Wax, Waxb, NW);
    cvt_bf16<<<dim3(NW / 1024), dim3(256), 0, stream>>>(Waa, PB,   NW);   // PB[0] = W
    cvt_bf16<<<dim3(NW / 1024), dim3(256), 0, stream>>>(Wy,  Wyb,  NW);

    dim3 grid(256, 8), blk(256);
    // Phase A: U = X @ Wax^T + ba   (f32 A-operand, rows b*512+t -> t*64+b, bf16 out)
    gemm_bt<true, false, 1><<<grid, blk, 0, stream>>>(X, Waxb, ba, UA);

    // Powers of W (log-depth; powers commute so only P_{2^k}^T is ever needed):
    transpose_bf16<<<dim3(16, 16), blk, 0, stream>>>(PB, Tb);              // W^T
    powmul<<<dim3(8, 8, 1), blk, 0, stream>>>(PB, Tb, PB + 1 * MM);        // P2 = W*W
    transpose_bf16<<<dim3(16, 16), blk, 0, stream>>>(PB + 1 * MM, Tb);     // P2^T
    powmul<<<dim3(8, 8, 2), blk, 0, stream>>>(PB, Tb, PB + 2 * MM);        // P3,P4 = {P1,P2}*P2
    transpose_bf16<<<dim3(16, 16), blk, 0, stream>>>(PB + 3 * MM, Tb);     // P4^T
    powmul<<<dim3(8, 8, 4), blk, 0, stream>>>(PB, Tb, PB + 4 * MM);        // P5..P8 = {P1..P4}*P4
    transpose_bf16<<<dim3(16, 16), blk, 0, stream>>>(PB + 7 * MM, Tb);     // P8^T
    powmul<<<dim3(8, 8, 8), blk, 0, stream>>>(PB, Tb, PB + 8 * MM);        // P9..P16 = {P1..P8}*P8

    // Local chunk scans: depth 15, all 32 chunks in parallel per launch.
    for (int j = 1; j < 16; ++j)
        local_step<<<dim3(32, 8), blk, 0, stream>>>(PB, UA, j);

    // Carry scan over chunk ends: CIN[c] = A_end[c-1]; CIN[0] = 0.
    zero_bf16<<<dim3(32), dim3(256), 0, stream>>>(CIN, 65536);
    for (int c = 1; c < 32; ++c)
        carry_step<<<dim3(256), dim3(64), 0, stream>>>(
            PB + 15 * MM,
            UA  + (size_t)((c - 1) * 16 + 15) * 65536,
            CIN + (size_t)(c - 1) * 65536,
            CIN + (size_t)c * 65536);

    // Fix-up: UA[c*16+j] += CIN[c] @ (W^{j+1})^T, one parallel launch.
    fixup_k<<<dim3(16, 8, 16), blk, 0, stream>>>(CIN, PB, UA);

    // Phase C: Y = A @ Wy^T + by    (rows t*64+b -> b*512+t, f32 out to d_out)
    gemm_bt<false, true, 2><<<grid, blk, 0, stream>>>(UA, Wyb, by, (float*)d_out);
}

// Round 2
// 928.130 us; speedup vs baseline: 2.8120x; 1.0474x over previous
//
#include <hip/hip_runtime.h>
#include <hip/hip_bf16.h>
#include <stdint.h>
#include <stddef.h>

using bf16 = __hip_bfloat16;
typedef short s16x8 __attribute__((ext_vector_type(8)));   // 8 bf16 = one MFMA frag (4 VGPRs)
typedef float f32x4 __attribute__((ext_vector_type(4)));

#define MFMA16(a, b, c) __builtin_amdgcn_mfma_f32_16x16x32_bf16((a), (b), (c), 0, 0, 0)

typedef __attribute__((address_space(1))) void gvoid;
typedef __attribute__((address_space(3))) void lvoid;
// global -> LDS direct copy, 16B per lane; LDS dest = wave-uniform base + lane*16
#define GLL16(gp, lp) __builtin_amdgcn_global_load_lds((gvoid*)(void*)(gp), (lvoid*)(lp), 16, 0, 0)

__device__ __forceinline__ short f2bf(float x) {
    bf16 h = __float2bfloat16(x);
    return __builtin_bit_cast(short, h);
}

// f32 -> bf16 elementwise, n % 1024 == 0, grid*block*4 == n
__global__ void cvt_bf16(const float* __restrict__ in, bf16* __restrict__ out, int n) {
    int i = (blockIdx.x * blockDim.x + threadIdx.x) * 4;
    if (i < n) {
        float4 v = *(const float4*)(in + i);
        out[i + 0] = __float2bfloat16(v.x);
        out[i + 1] = __float2bfloat16(v.y);
        out[i + 2] = __float2bfloat16(v.z);
        out[i + 3] = __float2bfloat16(v.w);
    }
}

// zero n bf16 (n % 2048 == 0), grid*block*8 == n
__global__ void zero_bf16(bf16* __restrict__ p, int n) {
    int i = (blockIdx.x * blockDim.x + threadIdx.x) * 8;
    if (i < n) {
        s16x8 z = {0, 0, 0, 0, 0, 0, 0, 0};
        *(s16x8*)(p + i) = z;
    }
}

// 1024x1024 bf16 transpose: out = in^T.  grid (16,16), block 256.
__global__ __launch_bounds__(256) void transpose_bf16(
    const bf16* __restrict__ in, bf16* __restrict__ out)
{
    __shared__ bf16 t[64][72];
    const int bx = blockIdx.x * 64, by = blockIdx.y * 64;
    const int tid = threadIdx.x;
#pragma unroll
    for (int i = 0; i < 2; ++i) {
        const int r = (tid >> 3) + i * 32, c = (tid & 7) * 8;
        *(s16x8*)&t[r][c] = *(const s16x8*)(in + (size_t)(bx + r) * 1024 + by + c);
    }
    __syncthreads();
#pragma unroll
    for (int i = 0; i < 2; ++i) {
        const int r = (tid >> 3) + i * 32, c = (tid & 7) * 8;
        s16x8 v;
#pragma unroll
        for (int k = 0; k < 8; ++k) v[k] = __builtin_bit_cast(short, t[c + k][r]);
        *(s16x8*)(out + (size_t)(by + r) * 1024 + bx + c) = v;
    }
}

// ---------------------------------------------------------------------------
// C[om(m)][n] = bias[n] + sum_k A[m][k] * Bt[n][k]     (K = N = 1024)
// A_F32: A is f32, staged via register convert + ds_write_b128 (XOR-swizzled
//        chunk layout identical to the GLL16 path). Else A is bf16 via GLL16.
// OUT_F32: store f32 (+f32 bias) else bf16.  bias always f32.
// REMAP: 0 none; 1 m=b*512+t -> t*64+b ; 2 m=t*64+b -> b*512+t
// 128x128 tile, BK=64, 4 waves each 64x64 (m97-verified structure).
// Block->tile mapping swizzled (T1): grid is (256,8); linear id is remapped so
// each XCD owns a contiguous band of m-slabs and the 8 n-tiles of one m-slab
// are dispatched consecutively (A-slab L2 reuse 8x). 2048 % 8 == 0 -> bijective.
// ---------------------------------------------------------------------------
template<bool A_F32, bool OUT_F32, int REMAP>
__global__ __launch_bounds__(256) void gemm_bt(
    const void* __restrict__ Ap, const bf16* __restrict__ Bt,
    const float* __restrict__ bias, void* __restrict__ Cp)
{
    __shared__ __align__(16) bf16 lA[128 * 64];
    __shared__ __align__(16) bf16 lB[128 * 64];

    const int tid  = threadIdx.x;
    const int lane = tid & 63, wv = tid >> 6;
    const int wm = wv & 1, wn = wv >> 1;
    const int quad = lane >> 4, l16 = lane & 15;

    // XCD-aware swizzle: lid -> wid (XCD-contiguous), then n-tile fastest.
    const int lid = blockIdx.y * 256 + blockIdx.x;      // grid (256,8), x fastest
    const int wid = (lid & 7) * 256 + (lid >> 3);       // 2048/8 = 256 per XCD
    const int m0 = (wid >> 3) * 128;                    // 256 m-tiles
    const int n0 = (wid & 7) * 128;                     // 8 n-tiles

    const int sr = lane >> 3;
    const int sc = ((lane & 7) ^ sr) * 8;   // element offset of swizzled 16B chunk

    const int ar = tid >> 1;
    const int ah = tid & 1;

    f32x4 acc[4][4] = {};

    for (int ko = 0; ko < 1024; ko += 64) {
        if constexpr (A_F32) {
            const float* Af = (const float*)Ap;
#pragma unroll
            for (int i = 0; i < 4; ++i) {
                const int c = ah * 4 + i;                    // source chunk 0..7
                const float* src = Af + (size_t)(m0 + ar) * 1024 + ko + c * 8;
                float4 v0 = *(const float4*)(src);
                float4 v1 = *(const float4*)(src + 4);
                s16x8 w;
                w[0] = f2bf(v0.x); w[1] = f2bf(v0.y); w[2] = f2bf(v0.z); w[3] = f2bf(v0.w);
                w[4] = f2bf(v1.x); w[5] = f2bf(v1.y); w[6] = f2bf(v1.z); w[7] = f2bf(v1.w);
                *(s16x8*)((char*)lA + ar * 128 + ((c ^ (ar & 7)) << 4)) = w;
            }
#pragma unroll
            for (int qi = 0; qi < 4; ++qi) {
                const int q = wv * 4 + qi;
                GLL16(Bt + (size_t)(n0 + q * 8 + sr) * 1024 + ko + sc, (char*)lB + q * 1024);
            }
        } else {
            const bf16* Ab = (const bf16*)Ap;
#pragma unroll
            for (int qi = 0; qi < 4; ++qi) {
                const int q = wv * 4 + qi;
                GLL16(Ab + (size_t)(m0 + q * 8 + sr) * 1024 + ko + sc, (char*)lA + q * 1024);
                GLL16(Bt + (size_t)(n0 + q * 8 + sr) * 1024 + ko + sc, (char*)lB + q * 1024);
            }
        }
        __syncthreads();   // drains vmcnt + lgkmcnt before s_barrier
#pragma unroll
        for (int kc = 0; kc < 2; ++kc) {
            s16x8 af[4], bg[4];
#pragma unroll
            for (int mt = 0; mt < 4; ++mt) {
                const int r = 64 * wm + 16 * mt + l16;
                const int c = kc * 4 + quad;
                af[mt] = *(const s16x8*)((const char*)lA + r * 128 + ((c ^ (r & 7)) * 16));
            }
#pragma unroll
            for (int nt = 0; nt < 4; ++nt) {
                const int r = 64 * wn + 16 * nt + l16;
                const int c = kc * 4 + quad;
                bg[nt] = *(const s16x8*)((const char*)lB + r * 128 + ((c ^ (r & 7)) * 16));
            }
#pragma unroll
            for (int mt = 0; mt < 4; ++mt)
#pragma unroll
                for (int nt = 0; nt < 4; ++nt)
                    acc[mt][nt] = MFMA16(af[mt], bg[nt], acc[mt][nt]);
        }
        __syncthreads();
    }

    float bv[4];
#pragma unroll
    for (int nt = 0; nt < 4; ++nt)
        bv[nt] = bias[n0 + 64 * wn + 16 * nt + l16];

    // D layout: row = quad*4 + reg, col = lane&15  (m89/m91-verified)
#pragma unroll
    for (int mt = 0; mt < 4; ++mt) {
#pragma unroll
        for (int r = 0; r < 4; ++r) {
            const int m = m0 + 64 * wm + 16 * mt + 4 * quad + r;
            int om = m;
            if constexpr (REMAP == 1)      om = ((m & 511) << 6) | (m >> 9); // b*512+t -> t*64+b
            else if constexpr (REMAP == 2) om = ((m & 63) << 9) | (m >> 6);  // t*64+b -> b*512+t
#pragma unroll
            for (int nt = 0; nt < 4; ++nt) {
                const int n = n0 + 64 * wn + 16 * nt + l16;
                const float val = acc[mt][nt][r] + bv[nt];
                if constexpr (OUT_F32) ((float*)Cp)[(size_t)om * 1024 + n] = val;
                else ((bf16*)Cp)[(size_t)om * 1024 + n] = __float2bfloat16(val);
            }
        }
    }
}

// ---------------------------------------------------------------------------
// Power chain: D[z] = A[z] @ Bt^T,  A = Abase + z*1M, D = Dbase + z*1M (elems).
// Same 128x128 structure as gemm_bt, no bias, bf16 out.  grid (8, 8, batch).
// ---------------------------------------------------------------------------
__global__ __launch_bounds__(256) void powmul(
    const bf16* __restrict__ Abase, const bf16* __restrict__ Bt,
    bf16* __restrict__ Dbase)
{
    __shared__ __align__(16) bf16 lA[128 * 64];
    __shared__ __align__(16) bf16 lB[128 * 64];
    const int tid  = threadIdx.x;
    const int lane = tid & 63, wv = tid >> 6;
    const int wm = wv & 1, wn = wv >> 1;
    const int quad = lane >> 4, l16 = lane & 15;
    const int m0 = blockIdx.x * 128, n0 = blockIdx.y * 128;
    const bf16* A = Abase + (size_t)blockIdx.z * 1048576;
    bf16* D       = Dbase + (size_t)blockIdx.z * 1048576;
    const int sr = lane >> 3;
    const int sc = ((lane & 7) ^ sr) * 8;

    f32x4 acc[4][4] = {};
    for (int ko = 0; ko < 1024; ko += 64) {
#pragma unroll
        for (int qi = 0; qi < 4; ++qi) {
            const int q = wv * 4 + qi;
            GLL16(A  + (size_t)(m0 + q * 8 + sr) * 1024 + ko + sc, (char*)lA + q * 1024);
            GLL16(Bt + (size_t)(n0 + q * 8 + sr) * 1024 + ko + sc, (char*)lB + q * 1024);
        }
        __syncthreads();
#pragma unroll
        for (int kc = 0; kc < 2; ++kc) {
            s16x8 af[4], bg[4];
#pragma unroll
            for (int mt = 0; mt < 4; ++mt) {
                const int r = 64 * wm + 16 * mt + l16;
                const int c = kc * 4 + quad;
                af[mt] = *(const s16x8*)((const char*)lA + r * 128 + ((c ^ (r & 7)) * 16));
            }
#pragma unroll
            for (int nt = 0; nt < 4; ++nt) {
                const int r = 64 * wn + 16 * nt + l16;
                const int c = kc * 4 + quad;
                bg[nt] = *(const s16x8*)((const char*)lB + r * 128 + ((c ^ (r & 7)) * 16));
            }
#pragma unroll
            for (int mt = 0; mt < 4; ++mt)
#pragma unroll
                for (int nt = 0; nt < 4; ++nt)
                    acc[mt][nt] = MFMA16(af[mt], bg[nt], acc[mt][nt]);
        }
        __syncthreads();
    }
#pragma unroll
    for (int mt = 0; mt < 4; ++mt)
#pragma unroll
        for (int r = 0; r < 4; ++r) {
            const int m = m0 + 64 * wm + 16 * mt + 4 * quad + r;
#pragma unroll
            for (int nt = 0; nt < 4; ++nt) {
                const int n = n0 + 64 * wn + 16 * nt + l16;
                D[(size_t)m * 1024 + n] = __float2bfloat16(acc[mt][nt][r]);
            }
        }
}

// ---------------------------------------------------------------------------
// Local scan step j: for every chunk c (blockIdx.x), rows t = c*16+j:
//   UA[t] += UA[t-1] @ Waa^T     (RMW epilogue; UA layout [t][b=64][1024])
// 64x128 tile, 4 waves each 64 rows x 32 cols.  grid (32, 8).
// ---------------------------------------------------------------------------
__global__ __launch_bounds__(256) void local_step(
    const bf16* __restrict__ Bt, bf16* __restrict__ UA, int j)
{
    __shared__ __align__(16) bf16 lA[64 * 64];
    __shared__ __align__(16) bf16 lB[128 * 64];
    const int tid = threadIdx.x;
    const int lane = tid & 63, wv = tid >> 6;
    const int quad = lane >> 4, l16 = lane & 15;
    const int n0 = blockIdx.y * 128;
    const int t = blockIdx.x * 16 + j;
    const bf16* src = UA + (size_t)(t - 1) * 64 * 1024;
    bf16* dst       = UA + (size_t)t * 64 * 1024;
    const int sr = lane >> 3;
    const int sc = ((lane & 7) ^ sr) * 8;

    f32x4 acc[4][2] = {};
    for (int ko = 0; ko < 1024; ko += 64) {
#pragma unroll
        for (int qi = 0; qi < 2; ++qi) {
            const int q = wv * 2 + qi;
            GLL16(src + (size_t)(q * 8 + sr) * 1024 + ko + sc, (char*)lA + q * 1024);
        }
#pragma unroll
        for (int qi = 0; qi < 4; ++qi) {
            const int q = wv * 4 + qi;
            GLL16(Bt + (size_t)(n0 + q * 8 + sr) * 1024 + ko + sc, (char*)lB + q * 1024);
        }
        __syncthreads();
#pragma unroll
        for (int kc = 0; kc < 2; ++kc) {
            s16x8 af[4], bg[2];
#pragma unroll
            for (int mt = 0; mt < 4; ++mt) {
                const int r = 16 * mt + l16;
                const int c = kc * 4 + quad;
                af[mt] = *(const s16x8*)((const char*)lA + r * 128 + ((c ^ (r & 7)) * 16));
            }
#pragma unroll
            for (int nt = 0; nt < 2; ++nt) {
                const int r = 32 * wv + 16 * nt + l16;
                const int c = kc * 4 + quad;
                bg[nt] = *(const s16x8*)((const char*)lB + r * 128 + ((c ^ (r & 7)) * 16));
            }
#pragma unroll
            for (int mt = 0; mt < 4; ++mt)
#pragma unroll
                for (int nt = 0; nt < 2; ++nt)
                    acc[mt][nt] = MFMA16(af[mt], bg[nt], acc[mt][nt]);
        }
        __syncthreads();
    }
#pragma unroll
    for (int mt = 0; mt < 4; ++mt)
#pragma unroll
        for (int r = 0; r < 4; ++r) {
            const int b = 16 * mt + 4 * quad + r;
#pragma unroll
            for (int nt = 0; nt < 2; ++nt) {
                const int n = n0 + 32 * wv + 16 * nt + l16;
                bf16* p = dst + (size_t)b * 1024 + n;
                *p = __float2bfloat16(acc[mt][nt][r] + __bfloat162float(*p));
            }
        }
}

// ---------------------------------------------------------------------------
// Carry step: dst[b][n] = lend[b][n] + sum_k src[b][k] * P16[n][k]
// (dst = CIN[c], src = CIN[c-1], lend = UA rows of t=(c-1)*16+15)
// Identical structure to the verified scan_step: 256 blocks x 1 wave.
// ---------------------------------------------------------------------------
__global__ __launch_bounds__(64, 1) void carry_step(
    const bf16* __restrict__ P16, const bf16* __restrict__ lend,
    const bf16* __restrict__ src, bf16* __restrict__ dst)
{
    const int lane = threadIdx.x;
    const int quad = lane >> 4, l16 = lane & 15;
    const int bi = blockIdx.x & 3, nj = blockIdx.x >> 2;

    const bf16* arow = src + ((size_t)(16 * bi + l16)) * 1024;
    const bf16* wrow = P16 + ((size_t)(16 * nj + l16)) * 1024;

    const bf16* urow = lend + ((size_t)(16 * bi + 4 * quad)) * 1024 + 16 * nj + l16;
    f32x4 acc;
#pragma unroll
    for (int rr = 0; rr < 4; ++rr)
        acc[rr] = __bfloat162float(urow[(size_t)rr * 1024]);

    s16x8 av[32], wf[32];
#pragma unroll
    for (int kc = 0; kc < 32; ++kc) {
        av[kc] = *(const s16x8*)(arow + kc * 32 + quad * 8);
        wf[kc] = *(const s16x8*)(wrow + kc * 32 + quad * 8);
    }
#pragma unroll
    for (int kc = 0; kc < 32; ++kc)
        acc = MFMA16(av[kc], wf[kc], acc);

    bf16* drow = dst + ((size_t)(16 * bi + 4 * quad)) * 1024 + 16 * nj + l16;
#pragma unroll
    for (int rr = 0; rr < 4; ++rr)
        drow[(size_t)rr * 1024] = __float2bfloat16(acc[rr]);
}

// ---------------------------------------------------------------------------
// Fix-up (one launch, fully parallel):
//   UA[(c*16+j)*64 + b][n] += sum_k CIN[c*64 + b][k] * P_{j+1}[n][k]
// A = CIN (2048 contiguous rows), Bt = PB + j*1M, j = blockIdx.z.
// 128x128 tile gemm_bt structure with RMW row-mapped epilogue. grid (16,8,16).
// Per-z-slice block->tile swizzle (T1): 128 blocks, n-tile fastest per m-slab.
// ---------------------------------------------------------------------------
__global__ __launch_bounds__(256) void fixup_k(
    const bf16* __restrict__ CIN, const bf16* __restrict__ PBase,
    bf16* __restrict__ UA)
{
    __shared__ __align__(16) bf16 lA[128 * 64];
    __shared__ __align__(16) bf16 lB[128 * 64];
    const int tid  = threadIdx.x;
    const int lane = tid & 63, wv = tid >> 6;
    const int wm = wv & 1, wn = wv >> 1;
    const int quad = lane >> 4, l16 = lane & 15;

    const int lid = blockIdx.y * 16 + blockIdx.x;   // 0..127 within z-slice
    const int wid = (lid & 7) * 16 + (lid >> 3);    // XCD-contiguous (128/8 = 16)
    const int m0 = (wid >> 3) * 128;                // 16 m-tiles
    const int n0 = (wid & 7) * 128;                 // 8 n-tiles

    const int j = blockIdx.z;
    const bf16* Bt = PBase + (size_t)j * 1048576;
    const int sr = lane >> 3;
    const int sc = ((lane & 7) ^ sr) * 8;

    f32x4 acc[4][4] = {};
    for (int ko = 0; ko < 1024; ko += 64) {
#pragma unroll
        for (int qi = 0; qi < 4; ++qi) {
            const int q = wv * 4 + qi;
            GLL16(CIN + (size_t)(m0 + q * 8 + sr) * 1024 + ko + sc, (char*)lA + q * 1024);
            GLL16(Bt  + (size_t)(n0 + q * 8 + sr) * 1024 + ko + sc, (char*)lB + q * 1024);
        }
        __syncthreads();
#pragma unroll
        for (int kc = 0; kc < 2; ++kc) {
            s16x8 af[4], bg[4];
#pragma unroll
            for (int mt = 0; mt < 4; ++mt) {
                const int r = 64 * wm + 16 * mt + l16;
                const int c = kc * 4 + quad;
                af[mt] = *(const s16x8*)((const char*)lA + r * 128 + ((c ^ (r & 7)) * 16));
            }
#pragma unroll
            for (int nt = 0; nt < 4; ++nt) {
                const int r = 64 * wn + 16 * nt + l16;
                const int c = kc * 4 + quad;
                bg[nt] = *(const s16x8*)((const char*)lB + r * 128 + ((c ^ (r & 7)) * 16));
            }
#pragma unroll
            for (int mt = 0; mt < 4; ++mt)
#pragma unroll
                for (int nt = 0; nt < 4; ++nt)
                    acc[mt][nt] = MFMA16(af[mt], bg[nt], acc[mt][nt]);
        }
        __syncthreads();
    }
#pragma unroll
    for (int mt = 0; mt < 4; ++mt)
#pragma unroll
        for (int r = 0; r < 4; ++r) {
            const int vm = m0 + 64 * wm + 16 * mt + 4 * quad + r;   // c*64 + b
            const size_t grow = (size_t)(((vm >> 6) * 16 + j) * 64 + (vm & 63));
#pragma unroll
            for (int nt = 0; nt < 4; ++nt) {
                const int n = n0 + 64 * wn + 16 * nt + l16;
                bf16* p = UA + grow * 1024 + n;
                *p = __float2bfloat16(acc[mt][nt][r] + __bfloat162float(*p));
            }
        }
}

// ---------------------------------------------------------------------------
// Blocked linear scan, S=16 chunk, G=32 chunks:
//   A[t] = U[t] + A[t-1]@W^T  ==  local chunk scans (depth 15, parallel over
//   chunks) + carry scan over chunk ends with W^16 (depth 31, tiny) + one
//   parallel fix-up with powers W^1..W^16.
// ---------------------------------------------------------------------------
extern "C" void kernel_launch(void* const* d_in, const int* in_sizes, int n_in,
                              void* d_out, int out_size, void* d_ws, size_t ws_size,
                              hipStream_t stream) {
    const float* X   = (const float*)d_in[0];   // [64,512,1024] f32
    const float* Wax = (const float*)d_in[1];   // [1024,1024]   f32
    const float* Waa = (const float*)d_in[2];   // [1024,1024]   f32
    const float* ba  = (const float*)d_in[3];   // [1024]        f32
    const float* Wy  = (const float*)d_in[4];   // [1024,1024]   f32
    const float* by  = (const float*)d_in[5];   // [1024]        f32

    char* ws = (char*)d_ws;
    bf16* UA   = (bf16*)ws;                       // 64 MB: [512][64][1024]
    bf16* PB   = (bf16*)(ws + 67108864);          // 32 MB: PB[k] = W^{k+1}, k=0..15
    bf16* Waxb = (bf16*)(ws + 100663296);         // 2 MB
    bf16* Wyb  = (bf16*)(ws + 102760448);         // 2 MB
    bf16* CIN  = (bf16*)(ws + 104857600);         // 4 MB: [32][64][1024] carry-in per chunk
    bf16* Tb   = CIN;                             // 2 MB transpose scratch (dead before carries)
    const size_t MM = 1048576;                    // elems per 1024x1024 matrix

    const int NW = 1024 * 1024;
    cvt_bf16<<<dim3(NW / 1024), dim3(256), 0, stream>>>(Wax, Waxb, NW);
    cvt_bf16<<<dim3(NW / 1024), dim3(256), 0, stream>>>(Waa, PB,   NW);   // PB[0] = W
    cvt_bf16<<<dim3(NW / 1024), dim3(256), 0, stream>>>(Wy,  Wyb,  NW);

    dim3 grid(256, 8), blk(256);
    // Phase A: U = X @ Wax^T + ba   (f32 A-operand, rows b*512+t -> t*64+b, bf16 out)
    gemm_bt<true, false, 1><<<grid, blk, 0, stream>>>(X, Waxb, ba, UA);

    // Powers of W (log-depth; powers commute so only P_{2^k}^T is ever needed):
    transpose_bf16<<<dim3(16, 16), blk, 0, stream>>>(PB, Tb);              // W^T
    powmul<<<dim3(8, 8, 1), blk, 0, stream>>>(PB, Tb, PB + 1 * MM);        // P2 = W*W
    transpose_bf16<<<dim3(16, 16), blk, 0, stream>>>(PB + 1 * MM, Tb);     // P2^T
    powmul<<<dim3(8, 8, 2), blk, 0, stream>>>(PB, Tb, PB + 2 * MM);        // P3,P4 = {P1,P2}*P2
    transpose_bf16<<<dim3(16, 16), blk, 0, stream>>>(PB + 3 * MM, Tb);     // P4^T
    powmul<<<dim3(8, 8, 4), blk, 0, stream>>>(PB, Tb, PB + 4 * MM);        // P5..P8 = {P1..P4}*P4
    transpose_bf16<<<dim3(16, 16), blk, 0, stream>>>(PB + 7 * MM, Tb);     // P8^T
    powmul<<<dim3(8, 8, 8), blk, 0, stream>>>(PB, Tb, PB + 8 * MM);        // P9..P16 = {P1..P8}*P8

    // Local chunk scans: depth 15, all 32 chunks in parallel per launch.
    for (int j = 1; j < 16; ++j)
        local_step<<<dim3(32, 8), blk, 0, stream>>>(PB, UA, j);

    // Carry scan over chunk ends: CIN[c] = A_end[c-1]; CIN[0] = 0.
    zero_bf16<<<dim3(32), dim3(256), 0, stream>>>(CIN, 65536);
    for (int c = 1; c < 32; ++c)
        carry_step<<<dim3(256), dim3(64), 0, stream>>>(
            PB + 15 * MM,
            UA  + (size_t)((c - 1) * 16 + 15) * 65536,
            CIN + (size_t)(c - 1) * 65536,
            CIN + (size_t)c * 65536);

    // Fix-up: UA[c*16+j] += CIN[c] @ (W^{j+1})^T, one parallel launch.
    fixup_k<<<dim3(16, 8, 16), blk, 0, stream>>>(CIN, PB, UA);

    // Phase C: Y = A @ Wy^T + by    (rows t*64+b -> b*512+t, f32 out to d_out)
    gemm_bt<false, true, 2><<<grid, blk, 0, stream>>>(UA, Wyb, by, (float*)d_out);
}